// Round 2
// baseline (1281.471 us; speedup 1.0000x reference)
//
#include <hip/hip_runtime.h>
#include <math.h>

#define B 16
#define N 32
#define M 64
#define D 512
#define NM (N * M)          // 2048
#define NUM_NEGS 32
#define SMOOTHING 0.1f
#define TD0 (1.0f - SMOOTHING)                    // 0.9
#define TDN (SMOOTHING / (float)(NUM_NEGS - 1))   // 0.1/31
#define TDSUM (TD0 + (float)NUM_NEGS * TDN)       // 0.9 + 32*0.1/31

__global__ void init_acc_kernel(float* acc) {
    if (threadIdx.x < 4) acc[threadIdx.x] = 0.0f;
}

__global__ __launch_bounds__(256) void ce_main_kernel(
    const float* __restrict__ s,              // (B, NM, D)
    const float* __restrict__ c,              // (B, NM, D)
    const int* __restrict__ pad,              // (B, N, M, M) bool as int32
    const int* __restrict__ valid,            // (B, NM, NM) bool as int32
    const int* __restrict__ inds,             // (B*NM*NUM_NEGS, 3)
    float* __restrict__ acc)                  // [ce_sum, sim_sum, cnt]
{
    __shared__ float s_lds[D];
    __shared__ float dots[NUM_NEGS + 1];
    __shared__ int   colsh[NUM_NEGS + 1];
    __shared__ int   rowsh[NUM_NEGS + 1];   // source (b*NM+row) for the s side
    __shared__ unsigned char vmsk[NUM_NEGS + 1];

    const int bq = blockIdx.x;
    const int b  = bq / NM;
    const int q  = bq % NM;

    const int tid  = threadIdx.x;
    const int wave = tid >> 6;
    const int lane = tid & 63;

    // Stage this block's s-row (512 floats = 2 KB) into LDS.
    if (tid < 128) {
        reinterpret_cast<float4*>(s_lds)[tid] =
            reinterpret_cast<const float4*>(s + ((size_t)b * NM + q) * D)[tid];
    }

    // Entry 0 = diagonal (numerator, unmasked); entries 1..32 = sampled negs.
    if (tid < NUM_NEGS + 1) {
        int col, srow, vb;
        if (tid == 0) {
            col = b * NM + q; srow = b * NM + q; vb = 1;
        } else {
            size_t si = ((size_t)bq * NUM_NEGS + (tid - 1)) * 3;
            int bb = inds[si + 0];
            int rr = inds[si + 1];
            int cc = inds[si + 2];
            col  = bb * NM + cc;
            srow = bb * NM + rr;
            vb   = valid[((size_t)bb * NM + rr) * NM + cc] ? 1 : 0;
        }
        colsh[tid] = col;
        rowsh[tid] = srow;
        vmsk[tid]  = (unsigned char)vb;
    }
    __syncthreads();

    const int myrow = b * NM + q;

    // Each wave handles dots j = wave, wave+4, ... (33 total over 4 waves).
    for (int j = wave; j < NUM_NEGS + 1; j += 4) {
        const float* crow = c + (size_t)colsh[j] * D;
        float4 c0 = reinterpret_cast<const float4*>(crow)[lane];
        float4 c1 = reinterpret_cast<const float4*>(crow)[lane + 64];
        float4 s0, s1;
        if (rowsh[j] == myrow) {   // always true for the given inputs
            s0 = reinterpret_cast<const float4*>(s_lds)[lane];
            s1 = reinterpret_cast<const float4*>(s_lds)[lane + 64];
        } else {
            const float* srow = s + (size_t)rowsh[j] * D;
            s0 = reinterpret_cast<const float4*>(srow)[lane];
            s1 = reinterpret_cast<const float4*>(srow)[lane + 64];
        }
        float sum = c0.x * s0.x + c0.y * s0.y + c0.z * s0.z + c0.w * s0.w
                  + c1.x * s1.x + c1.y * s1.y + c1.z * s1.z + c1.w * s1.w;
        #pragma unroll
        for (int off = 32; off; off >>= 1) sum += __shfl_down(sum, off, 64);
        if (lane == 0) dots[j] = vmsk[j] ? sum : 0.0f;
    }
    __syncthreads();

    if (tid == 0) {
        const float num   = dots[0];
        const float pred0 = num;   // TEMPERATURE == 1.0
        float mx = pred0;
        #pragma unroll
        for (int j = 1; j <= NUM_NEGS; ++j) mx = fmaxf(mx, dots[j]);
        float se = expf(pred0 - mx);
        float sneg = 0.0f;
        #pragma unroll
        for (int j = 1; j <= NUM_NEGS; ++j) {
            se   += expf(dots[j] - mx);
            sneg += dots[j];
        }
        const float lse   = mx + logf(se);
        const float chunk = lse * TDSUM - (TD0 * pred0 + TDN * sneg);
        // not_padded = !padding_mask[b,n,m,0]; flat index = bq*M
        const float v   = pad[(size_t)bq * M] ? 0.0f : 1.0f;
        const float sim = 1.0f - fminf(fmaxf(num, -1.0f), 1.0f);
        atomicAdd(&acc[0], chunk * v);
        atomicAdd(&acc[1], sim * v);
        atomicAdd(&acc[2], v);
    }
}

__global__ void finalize_kernel(const float* __restrict__ acc,
                                float* __restrict__ out) {
    if (threadIdx.x == 0) {
        const float denom = acc[2];
        out[0] = acc[0] / denom;  // ce_loss
        out[1] = acc[1] / denom;  // sim_loss
    }
}

extern "C" void kernel_launch(void* const* d_in, const int* in_sizes, int n_in,
                              void* d_out, int out_size, void* d_ws, size_t ws_size,
                              hipStream_t stream) {
    const float* s_ptr   = (const float*)d_in[0];
    const float* c_ptr   = (const float*)d_in[1];
    const int*   pad_ptr = (const int*)d_in[2];
    const int*   val_ptr = (const int*)d_in[3];
    const int*   ind_ptr = (const int*)d_in[4];
    float*       out_ptr = (float*)d_out;
    float*       acc     = (float*)d_ws;

    init_acc_kernel<<<1, 64, 0, stream>>>(acc);
    ce_main_kernel<<<B * NM, 256, 0, stream>>>(s_ptr, c_ptr, pad_ptr, val_ptr,
                                               ind_ptr, acc);
    finalize_kernel<<<1, 64, 0, stream>>>(acc, out_ptr);
}

// Round 3
// 175.922 us; speedup vs baseline: 7.2843x; 7.2843x over previous
//
#include <hip/hip_runtime.h>
#include <math.h>

#define B 16
#define N 32
#define M 64
#define D 512
#define NM (N * M)          // 2048
#define NBQ (B * NM)        // 32768 blocks
#define NUM_NEGS 32
#define SMOOTHING 0.1f
#define TD0 (1.0f - SMOOTHING)                    // 0.9
#define TDN (SMOOTHING / (float)(NUM_NEGS - 1))   // 0.1/31
#define TDSUM (TD0 + (float)NUM_NEGS * TDN)

__global__ void init_acc_kernel(float* acc) {
    if (threadIdx.x < 4) acc[threadIdx.x] = 0.0f;
}

__global__ __launch_bounds__(256) void ce_main_kernel(
    const float* __restrict__ s,              // (B, NM, D)
    const float* __restrict__ c,              // (B, NM, D)
    const int* __restrict__ pad,              // (B, N, M, M) bool as int32
    const int* __restrict__ valid,            // (B, NM, NM) bool as int32
    const int* __restrict__ inds,             // (B*NM*NUM_NEGS, 3)
    float4* __restrict__ partials)            // (NBQ) {ce*v, sim*v, v, 0}
{
    __shared__ float dots[NUM_NEGS + 1];
    __shared__ int   colsh[NUM_NEGS + 1];
    __shared__ int   rowsh[NUM_NEGS + 1];
    __shared__ unsigned char vmsk[NUM_NEGS + 1];

    const int bq = blockIdx.x;                // == b*NM + q
    const int tid  = threadIdx.x;
    const int wave = tid >> 6;
    const int lane = tid & 63;

    // Entry 0 = diagonal (numerator); 1..32 = sampled negs.
    if (tid < NUM_NEGS + 1) {
        int col, srow, vb;
        if (tid == 0) {
            col = bq; srow = bq; vb = 1;
        } else {
            size_t si = ((size_t)bq * NUM_NEGS + (tid - 1)) * 3;
            int bb = inds[si + 0];
            int rr = inds[si + 1];
            int cc = inds[si + 2];
            col  = bb * NM + cc;
            srow = bb * NM + rr;
            vb   = valid[((size_t)bb * NM + rr) * NM + cc] ? 1 : 0;
        }
        colsh[tid] = col;
        rowsh[tid] = srow;
        vmsk[tid]  = (unsigned char)vb;
    }
    __syncthreads();

    const int myrow = bq;
    // Hoist this block's s-row fragment into registers (L1/L2 served).
    const float4* sp = reinterpret_cast<const float4*>(s + (size_t)myrow * D);
    const float4 s0 = sp[lane];
    const float4 s1 = sp[lane + 64];

    for (int j = wave; j < NUM_NEGS + 1; j += 4) {
        const float4* cp = reinterpret_cast<const float4*>(c + (size_t)colsh[j] * D);
        float4 c0 = cp[lane];
        float4 c1 = cp[lane + 64];
        float4 t0 = s0, t1 = s1;
        if (rowsh[j] != myrow) {   // never taken for the given inputs
            const float4* spx = reinterpret_cast<const float4*>(s + (size_t)rowsh[j] * D);
            t0 = spx[lane];
            t1 = spx[lane + 64];
        }
        float sum = c0.x * t0.x + c0.y * t0.y + c0.z * t0.z + c0.w * t0.w
                  + c1.x * t1.x + c1.y * t1.y + c1.z * t1.z + c1.w * t1.w;
        #pragma unroll
        for (int off = 32; off; off >>= 1) sum += __shfl_down(sum, off, 64);
        if (lane == 0) dots[j] = vmsk[j] ? sum : 0.0f;
    }
    __syncthreads();

    if (tid == 0) {
        const float num   = dots[0];
        const float pred0 = num;   // TEMPERATURE == 1.0
        float mx = pred0;
        #pragma unroll
        for (int j = 1; j <= NUM_NEGS; ++j) mx = fmaxf(mx, dots[j]);
        float se = expf(pred0 - mx);
        float sneg = 0.0f;
        #pragma unroll
        for (int j = 1; j <= NUM_NEGS; ++j) {
            se   += expf(dots[j] - mx);
            sneg += dots[j];
        }
        const float lse   = mx + logf(se);
        const float chunk = lse * TDSUM - (TD0 * pred0 + TDN * sneg);
        const float v     = pad[(size_t)bq * M] ? 0.0f : 1.0f;
        const float sim   = 1.0f - fminf(fmaxf(num, -1.0f), 1.0f);
        partials[bq] = make_float4(chunk * v, sim * v, v, 0.0f);
    }
}

// 64 blocks x 256 threads, grid-stride over NBQ partials, 3 atomics per block.
__global__ __launch_bounds__(256) void reduce_kernel(
    const float4* __restrict__ partials, float* __restrict__ acc)
{
    __shared__ float red[3][4];
    float a = 0.0f, bsum = 0.0f, cnt = 0.0f;
    for (int i = blockIdx.x * 256 + threadIdx.x; i < NBQ; i += 64 * 256) {
        float4 p = partials[i];
        a += p.x; bsum += p.y; cnt += p.z;
    }
    #pragma unroll
    for (int off = 32; off; off >>= 1) {
        a    += __shfl_down(a, off, 64);
        bsum += __shfl_down(bsum, off, 64);
        cnt  += __shfl_down(cnt, off, 64);
    }
    const int wave = threadIdx.x >> 6;
    const int lane = threadIdx.x & 63;
    if (lane == 0) { red[0][wave] = a; red[1][wave] = bsum; red[2][wave] = cnt; }
    __syncthreads();
    if (threadIdx.x == 0) {
        atomicAdd(&acc[0], red[0][0] + red[0][1] + red[0][2] + red[0][3]);
        atomicAdd(&acc[1], red[1][0] + red[1][1] + red[1][2] + red[1][3]);
        atomicAdd(&acc[2], red[2][0] + red[2][1] + red[2][2] + red[2][3]);
    }
}

__global__ void finalize_kernel(const float* __restrict__ acc,
                                float* __restrict__ out) {
    if (threadIdx.x == 0) {
        const float denom = acc[2];
        out[0] = acc[0] / denom;  // ce_loss
        out[1] = acc[1] / denom;  // sim_loss
    }
}

extern "C" void kernel_launch(void* const* d_in, const int* in_sizes, int n_in,
                              void* d_out, int out_size, void* d_ws, size_t ws_size,
                              hipStream_t stream) {
    const float* s_ptr   = (const float*)d_in[0];
    const float* c_ptr   = (const float*)d_in[1];
    const int*   pad_ptr = (const int*)d_in[2];
    const int*   val_ptr = (const int*)d_in[3];
    const int*   ind_ptr = (const int*)d_in[4];
    float*       out_ptr = (float*)d_out;

    // ws layout: [0..3] acc, [16..] float4 partials (16-float offset for alignment)
    float*  acc      = (float*)d_ws;
    float4* partials = (float4*)((char*)d_ws + 64);

    init_acc_kernel<<<1, 64, 0, stream>>>(acc);
    ce_main_kernel<<<NBQ, 256, 0, stream>>>(s_ptr, c_ptr, pad_ptr, val_ptr,
                                            ind_ptr, partials);
    reduce_kernel<<<64, 256, 0, stream>>>(partials, acc);
    finalize_kernel<<<1, 64, 0, stream>>>(acc, out_ptr);
}

// Round 4
// 149.478 us; speedup vs baseline: 8.5730x; 1.1769x over previous
//
#include <hip/hip_runtime.h>
#include <math.h>

#define B 16
#define N 32
#define M 64
#define D 512
#define NM (N * M)          // 2048
#define NBQ (B * NM)        // 32768
#define NUM_NEGS 32
#define SMOOTHING 0.1f
#define TD0 (1.0f - SMOOTHING)                    // 0.9
#define TDN (SMOOTHING / (float)(NUM_NEGS - 1))   // 0.1/31
#define TDSUM (TD0 + (float)NUM_NEGS * TDN)

__global__ __launch_bounds__(256) void ce_main_kernel(
    const float* __restrict__ s,              // (B, NM, D)
    const float* __restrict__ c,              // (B, NM, D)
    const int* __restrict__ pad,              // (B, N, M, M) bool as int32
    const int* __restrict__ valid,            // (B, NM, NM) bool as int32
    const int* __restrict__ inds,             // (B*NM*NUM_NEGS, 3)
    float4* __restrict__ partials)            // (NBQ) {ce*v, sim*v, v, 0}
{
    __shared__ float dots[NUM_NEGS + 1];
    __shared__ int   colsh[NUM_NEGS + 1];
    __shared__ int   rowsh[NUM_NEGS + 1];
    __shared__ unsigned char vmsk[NUM_NEGS + 1];

    // XCD-batch affinity swizzle: physical block p runs on XCD p%8 (round-robin
    // dispatch). Give XCD x batches {x, x+8} so each XCD's 4MB L2 holds its own
    // batch's 4MB c-panel instead of all 8 XCDs replicating the same panel.
    const int p  = blockIdx.x;
    const int x  = p & 7;
    const int i  = p >> 3;                    // 0..4095 within XCD
    const int b  = x + ((i >> 11) << 3);      // batch
    const int q  = i & (NM - 1);
    const int bq = b * NM + q;

    const int tid  = threadIdx.x;
    const int wave = tid >> 6;
    const int lane = tid & 63;

    // Entry 0 = diagonal (numerator); 1..32 = sampled negs.
    if (tid < NUM_NEGS + 1) {
        int col, srow, vb;
        if (tid == 0) {
            col = bq; srow = bq; vb = 1;
        } else {
            size_t si = ((size_t)bq * NUM_NEGS + (tid - 1)) * 3;
            int bb = inds[si + 0];
            int rr = inds[si + 1];
            int cc = inds[si + 2];
            col  = bb * NM + cc;
            srow = bb * NM + rr;
            vb   = valid[((size_t)bb * NM + rr) * NM + cc] ? 1 : 0;
        }
        colsh[tid] = col;
        rowsh[tid] = srow;
        vmsk[tid]  = (unsigned char)vb;
    }
    __syncthreads();

    const int myrow = bq;
    const float4* sp = reinterpret_cast<const float4*>(s + (size_t)myrow * D);
    const float4 s0 = sp[lane];
    const float4 s1 = sp[lane + 64];

    for (int j = wave; j < NUM_NEGS + 1; j += 4) {
        const float4* cp = reinterpret_cast<const float4*>(c + (size_t)colsh[j] * D);
        float4 c0 = cp[lane];
        float4 c1 = cp[lane + 64];
        float4 t0 = s0, t1 = s1;
        if (rowsh[j] != myrow) {   // never taken for the given inputs
            const float4* spx = reinterpret_cast<const float4*>(s + (size_t)rowsh[j] * D);
            t0 = spx[lane];
            t1 = spx[lane + 64];
        }
        float sum = c0.x * t0.x + c0.y * t0.y + c0.z * t0.z + c0.w * t0.w
                  + c1.x * t1.x + c1.y * t1.y + c1.z * t1.z + c1.w * t1.w;
        #pragma unroll
        for (int off = 32; off; off >>= 1) sum += __shfl_down(sum, off, 64);
        if (lane == 0) dots[j] = vmsk[j] ? sum : 0.0f;
    }
    __syncthreads();

    // Wave-parallel epilogue (was ~33 serial expf on tid 0).
    if (wave == 0) {
        const float dj = (lane <= NUM_NEGS) ? dots[lane] : -INFINITY;
        float mx = dj;
        #pragma unroll
        for (int off = 32; off; off >>= 1) mx = fmaxf(mx, __shfl_xor(mx, off, 64));
        float e  = (lane <= NUM_NEGS) ? expf(dj - mx) : 0.0f;
        float sn = (lane >= 1 && lane <= NUM_NEGS) ? dj : 0.0f;
        #pragma unroll
        for (int off = 32; off; off >>= 1) {
            e  += __shfl_xor(e, off, 64);
            sn += __shfl_xor(sn, off, 64);
        }
        if (lane == 0) {
            const float num   = dj;             // dots[0]
            const float lse   = mx + logf(e);
            const float chunk = lse * TDSUM - (TD0 * num + TDN * sn);
            const float v     = pad[(size_t)bq * M] ? 0.0f : 1.0f;
            const float sim   = 1.0f - fminf(fmaxf(num, -1.0f), 1.0f);
            partials[bq] = make_float4(chunk * v, sim * v, v, 0.0f);
        }
    }
}

// Stage 2: 64 blocks x 256 threads, grid-stride over NBQ, one partial per block.
__global__ __launch_bounds__(256) void reduce_kernel(
    const float4* __restrict__ partials, float4* __restrict__ blk)
{
    __shared__ float red[3][4];
    float a = 0.0f, bsum = 0.0f, cnt = 0.0f;
    for (int i = blockIdx.x * 256 + threadIdx.x; i < NBQ; i += 64 * 256) {
        float4 pr = partials[i];
        a += pr.x; bsum += pr.y; cnt += pr.z;
    }
    #pragma unroll
    for (int off = 32; off; off >>= 1) {
        a    += __shfl_down(a, off, 64);
        bsum += __shfl_down(bsum, off, 64);
        cnt  += __shfl_down(cnt, off, 64);
    }
    const int wave = threadIdx.x >> 6;
    const int lane = threadIdx.x & 63;
    if (lane == 0) { red[0][wave] = a; red[1][wave] = bsum; red[2][wave] = cnt; }
    __syncthreads();
    if (threadIdx.x == 0) {
        blk[blockIdx.x] = make_float4(red[0][0] + red[0][1] + red[0][2] + red[0][3],
                                      red[1][0] + red[1][1] + red[1][2] + red[1][3],
                                      red[2][0] + red[2][1] + red[2][2] + red[2][3],
                                      0.0f);
    }
}

// Stage 3: single wave sums the 64 block partials and writes the two losses.
__global__ void finalize_kernel(const float4* __restrict__ blk,
                                float* __restrict__ out) {
    const int lane = threadIdx.x & 63;
    float4 pr = blk[lane];
    float a = pr.x, bsum = pr.y, cnt = pr.z;
    #pragma unroll
    for (int off = 32; off; off >>= 1) {
        a    += __shfl_down(a, off, 64);
        bsum += __shfl_down(bsum, off, 64);
        cnt  += __shfl_down(cnt, off, 64);
    }
    if (lane == 0) {
        out[0] = a / cnt;     // ce_loss
        out[1] = bsum / cnt;  // sim_loss
    }
}

extern "C" void kernel_launch(void* const* d_in, const int* in_sizes, int n_in,
                              void* d_out, int out_size, void* d_ws, size_t ws_size,
                              hipStream_t stream) {
    const float* s_ptr   = (const float*)d_in[0];
    const float* c_ptr   = (const float*)d_in[1];
    const int*   pad_ptr = (const int*)d_in[2];
    const int*   val_ptr = (const int*)d_in[3];
    const int*   ind_ptr = (const int*)d_in[4];
    float*       out_ptr = (float*)d_out;

    // ws layout: [0 .. 512KB) float4 partials[NBQ]; [512KB ..) float4 blk[64]
    float4* partials = (float4*)d_ws;
    float4* blk      = (float4*)((char*)d_ws + (size_t)NBQ * sizeof(float4));

    ce_main_kernel<<<NBQ, 256, 0, stream>>>(s_ptr, c_ptr, pad_ptr, val_ptr,
                                            ind_ptr, partials);
    reduce_kernel<<<64, 256, 0, stream>>>(partials, blk);
    finalize_kernel<<<1, 64, 0, stream>>>(blk, out_ptr);
}